// Round 5
// baseline (59.462 us; speedup 1.0000x reference)
//
#include <hip/hip_runtime.h>
#include <math.h>

#define NF   32
#define HGT  512
#define WID  512
#define BAT  8
#define HW   (HGT*WID)        // 262144
#define NPIX (BAT*HW)         // 2097152
#define NROWS (2*NPIX)        // 4194304
#define TPB  256

#define TY   16               // tile height
#define TX   64               // tile width
#define NTILE (NPIX/(TY*TX))  // 2048 blocks

#define NC   7                // hrrp Chebyshev: degree 6, 7x7 coeffs
#define NCG  8                // g0 Chebyshev: degree 7, 8 coeffs

#define STR  67               // LDS row stride (odd -> conflict-free columns)

#define SC0_N (19*STR)        // 1273 staged c0 values
#define SW_N  (18*66)         // 1188 W points
#define SE_N  (17*65)         // 1105 ERR points

__device__ __forceinline__ float fast_tanh(float x) {
    float e = __expf(2.0f * x);
    return 1.0f - __fdividef(2.0f, e + 1.0f);
}

__device__ __forceinline__ float sload(const float* p) {
    return __int_as_float(__builtin_amdgcn_readfirstlane(__float_as_int(*p)));
}

__device__ __forceinline__ float chebG(float v, const float* CG) {
    float tt = 2.0f * v - 1.0f;
    float t0 = 1.0f, t1 = tt;
    float g = CG[0] + CG[1] * tt;
    #pragma unroll
    for (int p = 2; p < NCG; ++p) {
        float t2 = 2.0f * tt * t1 - t0;
        g += CG[p] * t2;
        t0 = t1; t1 = t2;
    }
    return g;
}

// ---------------- kT: build Chebyshev coefficients + zero the arrival counter
__global__ __launch_bounds__(128) void kT(
    const float* __restrict__ g0_w1, const float* __restrict__ g0_b1,
    const float* __restrict__ g0_w2, const float* __restrict__ g0_b2,
    const float* __restrict__ h_w1,  const float* __restrict__ h_b1,
    const float* __restrict__ h_w2,  const float* __restrict__ h_b2,
    float* __restrict__ CH, float* __restrict__ CG, unsigned* __restrict__ counter)
{
    __shared__ float cp[NC * NC];    // cos(p*pi*(i+0.5)/7)
    __shared__ float cg8[NCG * NCG]; // cos(p*pi*(i+0.5)/8)
    __shared__ float F[NC * NC];
    __shared__ float Fg[NCG];
    int t = threadIdx.x;
    if (t == 0) *counter = 0u;
    if (t < NC * NC) {
        int p = t / NC, i = t - NC * p;
        cp[t] = cosf((float)M_PI * (float)p * ((float)i + 0.5f) / (float)NC);
    } else if (t < NC * NC + NCG * NCG) {
        int u = t - NC * NC;
        int p = u / NCG, i = u - NCG * p;
        cg8[u] = cosf((float)M_PI * (float)p * ((float)i + 0.5f) / (float)NCG);
    }
    __syncthreads();
    if (t < NC * NC) {
        int i = t / NC, j = t - NC * i;
        float x = 0.5f * (cp[NC + i] + 1.0f);   // node_i
        float y = 0.5f * (cp[NC + j] + 1.0f);
        float s = 0.f;
        #pragma unroll
        for (int k = 0; k < NF; ++k) {
            float w0 = h_w1[k], w1 = h_w1[NF + k], bb = h_b1[k], w2 = h_w2[k];
            s += (fast_tanh(x * w0 + y * w1 + bb) + fast_tanh(y * w0 + x * w1 + bb)) * w2;
        }
        F[t] = 0.5f * s + h_b2[0];
    } else if (t < NC * NC + NCG) {
        int i = t - NC * NC;
        float x = 0.5f * (cg8[NCG + i] + 1.0f);
        float g = g0_b2[0];
        #pragma unroll
        for (int k = 0; k < NF; ++k)
            g += fast_tanh(x * g0_w1[k] + g0_b1[k]) * g0_w2[k];
        Fg[i] = g;
    }
    __syncthreads();
    if (t < NC * NC) {
        int p = t / NC, q = t - NC * p;
        float sum = 0.f;
        #pragma unroll
        for (int i = 0; i < NC; ++i)
            #pragma unroll
            for (int j = 0; j < NC; ++j)
                sum += F[i * NC + j] * cp[p * NC + i] * cp[q * NC + j];
        float kp = p ? 1.0f : 0.5f, kq = q ? 1.0f : 0.5f;
        CH[t] = (4.0f / (float)(NC * NC)) * kp * kq * sum;
    } else if (t < NC * NC + NCG) {
        int p = t - NC * NC;
        float sum = 0.f;
        #pragma unroll
        for (int i = 0; i < NCG; ++i)
            sum += Fg[i] * cg8[p * NCG + i];
        CG[p] = (2.0f / (float)NCG) * (p ? 1.0f : 0.5f) * sum;
    }
}

// ---------------- kF: fused tile kernel + last-block deterministic reduce
__global__ __launch_bounds__(TPB, 6) void kF(
    const float* __restrict__ c, const float* __restrict__ CHg,
    const float* __restrict__ CGg, float* __restrict__ partial,
    unsigned* __restrict__ counter, float* __restrict__ out)
{
    __shared__ float sC0[SC0_N + 7];   // 5120 B (also reused as double[256] by last block)
    __shared__ float sWU[18 * STR];
    __shared__ float sWL[18 * STR];
    __shared__ float sERR[17 * STR];
    __shared__ float wsum[4];
    __shared__ unsigned lastF;

    // coefficients pinned to SGPRs (wave-uniform)
    float CH[NC * NC], CG[NCG];
    #pragma unroll
    for (int i = 0; i < NC * NC; ++i) CH[i] = sload(CHg + i);
    #pragma unroll
    for (int i = 0; i < NCG; ++i)     CG[i] = sload(CGg + i);

    int tid = threadIdx.x;
    int bid = blockIdx.x;
    int b   = bid >> 8;               // 256 tiles per image
    int rem = bid & 255;
    int Y0  = (rem >> 3) << 4;        // 32 tiles vertically * 16
    int X0  = (rem & 7) << 6;         // 8 tiles horizontally * 64
    const float* c0g = c + (size_t)b * 2 * HW;
    const float* c1g = c0g + HW;

    // --- stage c0 (19x67, wrap), contiguous LDS
    #pragma unroll
    for (int r = 0; r < 5; ++r) {
        int i = tid + r * TPB;
        if (i < SC0_N) {
            int y = i / STR, x = i - y * STR;
            int gy = (Y0 + y - 2) & 511, gx = (X0 + x - 2) & 511;
            sC0[i] = c0g[(gy << 9) + gx];
        }
    }
    __syncthreads();

    // --- W: hrrp(center, up) and hrrp(center, left) via shared s_q(a)
    for (int i = tid; i < SW_N; i += TPB) {
        int y = i / 66, x = i - y * 66;
        int ci = (y + 1) * STR + (x + 1);
        float a  = sC0[ci];
        float uu = sC0[ci - STR];
        float ll = sC0[ci - 1];

        float ta = 2.0f * a - 1.0f;
        float T[NC];
        T[0] = 1.0f; T[1] = ta;
        #pragma unroll
        for (int p = 2; p < NC; ++p) T[p] = 2.0f * ta * T[p - 1] - T[p - 2];
        float s[NC];
        #pragma unroll
        for (int q = 0; q < NC; ++q) {
            float acc = CH[q];
            #pragma unroll
            for (int p = 1; p < NC; ++p) acc += CH[p * NC + q] * T[p];
            s[q] = acc;
        }
        float tu = 2.0f * uu - 1.0f;
        float u0 = 1.0f, u1 = tu;
        float wu = s[0] + s[1] * tu;
        #pragma unroll
        for (int q = 2; q < NC; ++q) {
            float u2 = 2.0f * tu * u1 - u0;
            wu += s[q] * u2;
            u0 = u1; u1 = u2;
        }
        float tl = 2.0f * ll - 1.0f;
        float l0 = 1.0f, l1 = tl;
        float wl = s[0] + s[1] * tl;
        #pragma unroll
        for (int q = 2; q < NC; ++q) {
            float l2 = 2.0f * tl * l1 - l0;
            wl += s[q] * l2;
            l0 = l1; l1 = l2;
        }
        sWU[y * STR + x] = wu;
        sWL[y * STR + x] = wl;
    }
    __syncthreads();

    // --- ERR over 17x65, G recomputed inline (cheap)
    #pragma unroll
    for (int r = 0; r < 5; ++r) {
        int i = tid + r * TPB;
        if (i < SE_N) {
            int y = i / 65, x = i - y * 65;
            int ci = (y + 1) * STR + (x + 1);
            float vc = sC0[ci];
            float lap = chebG(sC0[ci - STR], CG) + chebG(sC0[ci + STR], CG)
                      + chebG(sC0[ci - 1], CG) + chebG(sC0[ci + 1], CG)
                      - 4.0f * chebG(vc, CG);
            int gy = (Y0 + y - 1) & 511, gx = (X0 + x - 1) & 511;
            sERR[y * STR + x] = c1g[(gy << 9) + gx] - vc - lap;
        }
    }
    __syncthreads();

    // --- loss: each thread 4 pixels (exact trip)
    float acc = 0.f;
    int px = tid & 63, py0 = tid >> 6;
    #pragma unroll
    for (int r = 0; r < 4; ++r) {
        int py = py0 + (r << 2);
        int wp = (py + 1) * STR + (px + 1);
        float wu = sWU[wp], wl = sWL[wp];
        float oii_p = wu + wl + sWU[wp + STR] + sWL[wp + 1];
        float oii_u = sWU[wp - STR] + sWL[wp - STR] + wu + sWL[wp - STR + 1];
        float oii_l = sWU[wp - 1] + sWL[wp - 1] + sWU[wp + STR - 1] + wl;
        float e = sERR[wp], eu = sERR[wp - STR], el = sERR[wp - 1];
        float det0 = oii_p * oii_u - wu * wu;
        float l0 = det0 + __fdividef(e * e * oii_u + eu * eu * oii_p + 2.0f * e * eu * wu, det0);
        float det1 = oii_p * oii_l - wl * wl;
        float l1 = det1 + __fdividef(e * e * oii_l + el * el * oii_p + 2.0f * e * el * wl, det1);
        acc += l0 + l1;
    }
    #pragma unroll
    for (int off = 32; off > 0; off >>= 1)
        acc += __shfl_down(acc, off, 64);
    if ((tid & 63) == 0) wsum[tid >> 6] = acc;
    __syncthreads();

    if (tid == 0) {
        partial[bid] = wsum[0] + wsum[1] + wsum[2] + wsum[3];
        __threadfence();                       // release: make partial visible device-wide
        unsigned rk = atomicAdd(counter, 1u);  // device-scope
        lastF = (rk == NTILE - 1) ? 1u : 0u;
    }
    __syncthreads();

    if (lastF) {
        __threadfence();                       // acquire: invalidate local L2
        double a2 = 0.0;
        for (int i = tid; i < NTILE; i += TPB) // fixed tid-strided order -> deterministic
            a2 += (double)partial[i];
        double* smd = (double*)sC0;            // reuse LDS (all prior reads done)
        smd[tid] = a2;
        __syncthreads();
        #pragma unroll
        for (int s = TPB / 2; s > 0; s >>= 1) {
            if (tid < s) smd[tid] += smd[tid + s];
            __syncthreads();
        }
        if (tid == 0)
            out[0] = (float)(0.5 * smd[0] / (double)NROWS);
    }
}

extern "C" void kernel_launch(void* const* d_in, const int* in_sizes, int n_in,
                              void* d_out, int out_size, void* d_ws, size_t ws_size,
                              hipStream_t stream) {
    const float* c     = (const float*)d_in[0];
    const float* g0_w1 = (const float*)d_in[1];
    const float* g0_b1 = (const float*)d_in[2];
    const float* g0_w2 = (const float*)d_in[3];
    const float* g0_b2 = (const float*)d_in[4];
    const float* h_w1  = (const float*)d_in[5];
    const float* h_b1  = (const float*)d_in[6];
    const float* h_w2  = (const float*)d_in[7];
    const float* h_b2  = (const float*)d_in[8];
    float* out = (float*)d_out;

    // ws layout: CH | CG | partial | counter
    float* ws = (float*)d_ws;
    float* CH = ws;
    float* CG = CH + NC * NC;
    float* PARTIAL = CG + NCG;
    unsigned* COUNTER = (unsigned*)(PARTIAL + NTILE);

    kT<<<dim3(1), dim3(128), 0, stream>>>(
        g0_w1, g0_b1, g0_w2, g0_b2, h_w1, h_b1, h_w2, h_b2, CH, CG, COUNTER);
    kF<<<dim3(NTILE), dim3(TPB), 0, stream>>>(c, CH, CG, PARTIAL, COUNTER, out);
}

// Round 6
// 28.561 us; speedup vs baseline: 2.0819x; 2.0819x over previous
//
#include <hip/hip_runtime.h>
#include <math.h>

#define NF   32
#define HGT  512
#define WID  512
#define BAT  8
#define HW   (HGT*WID)        // 262144
#define NPIX (BAT*HW)         // 2097152
#define NROWS (2*NPIX)        // 4194304
#define TPB  256

#define TY   16               // tile height
#define TX   64               // tile width
#define NTILE (NPIX/(TY*TX))  // 2048 blocks

#define NC   5                // hrrp Chebyshev: degree 4, 5x5 coeffs
#define NCG  5                // g0 Chebyshev: degree 4

#define STR  68               // LDS row stride (words)

#define SC0_N (19*67)         // staged c0 values (compact index, padded store)
#define SW_N  (18*66)         // W points
#define SE_N  (17*65)         // ERR points

__device__ __forceinline__ float fast_tanh(float x) {
    float e = __expf(2.0f * x);
    return 1.0f - __fdividef(2.0f, e + 1.0f);
}

__device__ __forceinline__ float sload(const float* p) {
    return __int_as_float(__builtin_amdgcn_readfirstlane(__float_as_int(*p)));
}

__device__ __forceinline__ float chebG(float v, const float* CG) {
    float tt = 2.0f * v - 1.0f;
    float t0 = 1.0f, t1 = tt;
    float g = CG[0] + CG[1] * tt;
    #pragma unroll
    for (int p = 2; p < NCG; ++p) {
        float t2 = 2.0f * tt * t1 - t0;
        g += CG[p] * t2;
        t0 = t1; t1 = t2;
    }
    return g;
}

// ---------------- kT: build Chebyshev coefficients ----------------
__global__ __launch_bounds__(128) void kT(
    const float* __restrict__ g0_w1, const float* __restrict__ g0_b1,
    const float* __restrict__ g0_w2, const float* __restrict__ g0_b2,
    const float* __restrict__ h_w1,  const float* __restrict__ h_b1,
    const float* __restrict__ h_w2,  const float* __restrict__ h_b2,
    float* __restrict__ CH, float* __restrict__ CG)
{
    __shared__ float cp[NC * NC];    // cos(p*pi*(i+0.5)/NC)
    __shared__ float cg[NCG * NCG];  // cos(p*pi*(i+0.5)/NCG)
    __shared__ float F[NC * NC];
    __shared__ float Fg[NCG];
    int t = threadIdx.x;
    if (t < NC * NC) {
        int p = t / NC, i = t - NC * p;
        cp[t] = cosf((float)M_PI * (float)p * ((float)i + 0.5f) / (float)NC);
    } else if (t < NC * NC + NCG * NCG) {
        int u = t - NC * NC;
        int p = u / NCG, i = u - NCG * p;
        cg[u] = cosf((float)M_PI * (float)p * ((float)i + 0.5f) / (float)NCG);
    }
    __syncthreads();
    if (t < NC * NC) {
        int i = t / NC, j = t - NC * i;
        float x = 0.5f * (cp[NC + i] + 1.0f);   // node_i
        float y = 0.5f * (cp[NC + j] + 1.0f);
        float s = 0.f;
        #pragma unroll
        for (int k = 0; k < NF; ++k) {
            float w0 = h_w1[k], w1 = h_w1[NF + k], bb = h_b1[k], w2 = h_w2[k];
            s += (fast_tanh(x * w0 + y * w1 + bb) + fast_tanh(y * w0 + x * w1 + bb)) * w2;
        }
        F[t] = 0.5f * s + h_b2[0];
    } else if (t < NC * NC + NCG) {
        int i = t - NC * NC;
        float x = 0.5f * (cg[NCG + i] + 1.0f);
        float g = g0_b2[0];
        #pragma unroll
        for (int k = 0; k < NF; ++k)
            g += fast_tanh(x * g0_w1[k] + g0_b1[k]) * g0_w2[k];
        Fg[i] = g;
    }
    __syncthreads();
    if (t < NC * NC) {
        int p = t / NC, q = t - NC * p;
        float sum = 0.f;
        #pragma unroll
        for (int i = 0; i < NC; ++i)
            #pragma unroll
            for (int j = 0; j < NC; ++j)
                sum += F[i * NC + j] * cp[p * NC + i] * cp[q * NC + j];
        float kp = p ? 1.0f : 0.5f, kq = q ? 1.0f : 0.5f;
        CH[t] = (4.0f / (float)(NC * NC)) * kp * kq * sum;
    } else if (t < NC * NC + NCG) {
        int p = t - NC * NC;
        float sum = 0.f;
        #pragma unroll
        for (int i = 0; i < NCG; ++i)
            sum += Fg[i] * cg[p * NCG + i];
        CG[p] = (2.0f / (float)NCG) * (p ? 1.0f : 0.5f) * sum;
    }
}

// ---------------- kF: fused tile kernel ----------------
__global__ __launch_bounds__(TPB, 6) void kF(
    const float* __restrict__ c, const float* __restrict__ CHg,
    const float* __restrict__ CGg, float* __restrict__ partial)
{
    __shared__ float sC0[19 * STR];
    __shared__ float sG [19 * STR];
    __shared__ float sWU[18 * STR];
    __shared__ float sWL[18 * STR];
    __shared__ float sERR[17 * STR];
    __shared__ float wsum[4];

    // coefficients pinned to SGPRs (wave-uniform)
    float CH[NC * NC], CG[NCG];
    #pragma unroll
    for (int i = 0; i < NC * NC; ++i) CH[i] = sload(CHg + i);
    #pragma unroll
    for (int i = 0; i < NCG; ++i)     CG[i] = sload(CGg + i);

    int tid = threadIdx.x;
    int bid = blockIdx.x;
    int b   = bid >> 8;               // 256 tiles per image
    int rem = bid & 255;
    int Y0  = (rem >> 3) << 4;        // 32 tiles vertically * 16
    int X0  = (rem & 7) << 6;         // 8 tiles horizontally * 64
    const float* c0g = c + (size_t)b * 2 * HW;
    const float* c1g = c0g + HW;

    // --- stage c0 (19x67, wrap) and G = cheb(c0) in the same pass
    #pragma unroll
    for (int r = 0; r < 5; ++r) {
        int i = tid + r * TPB;
        if (i < SC0_N) {
            int y = i / 67, x = i - y * 67;
            int gy = (Y0 + y - 2) & 511, gx = (X0 + x - 2) & 511;
            float v = c0g[(gy << 9) + gx];
            sC0[y * STR + x] = v;
            sG [y * STR + x] = chebG(v, CG);
        }
    }
    __syncthreads();

    // --- W: hrrp(center, up) and hrrp(center, left) via shared s_q(a)
    #pragma unroll
    for (int r = 0; r < 5; ++r) {
        int i = tid + r * TPB;
        if (i < SW_N) {
            int y = i / 66, x = i - y * 66;
            int ci = (y + 1) * STR + (x + 1);
            float a  = sC0[ci];
            float uu = sC0[ci - STR];
            float ll = sC0[ci - 1];

            float ta = 2.0f * a - 1.0f;
            float T[NC];
            T[0] = 1.0f; T[1] = ta;
            #pragma unroll
            for (int p = 2; p < NC; ++p) T[p] = 2.0f * ta * T[p - 1] - T[p - 2];
            float s[NC];
            #pragma unroll
            for (int q = 0; q < NC; ++q) {
                float acc = CH[q];
                #pragma unroll
                for (int p = 1; p < NC; ++p) acc += CH[p * NC + q] * T[p];
                s[q] = acc;
            }
            float tu = 2.0f * uu - 1.0f;
            float u0 = 1.0f, u1 = tu;
            float wu = s[0] + s[1] * tu;
            #pragma unroll
            for (int q = 2; q < NC; ++q) {
                float u2 = 2.0f * tu * u1 - u0;
                wu += s[q] * u2;
                u0 = u1; u1 = u2;
            }
            float tl = 2.0f * ll - 1.0f;
            float l0 = 1.0f, l1 = tl;
            float wl = s[0] + s[1] * tl;
            #pragma unroll
            for (int q = 2; q < NC; ++q) {
                float l2 = 2.0f * tl * l1 - l0;
                wl += s[q] * l2;
                l0 = l1; l1 = l2;
            }
            sWU[y * STR + x] = wu;
            sWL[y * STR + x] = wl;
        }
    }
    __syncthreads();

    // --- ERR over 17x65 (reads sG)
    #pragma unroll
    for (int r = 0; r < 5; ++r) {
        int i = tid + r * TPB;
        if (i < SE_N) {
            int y = i / 65, x = i - y * 65;
            int ci = (y + 1) * STR + (x + 1);
            float lap = sG[ci - STR] + sG[ci + STR] + sG[ci - 1] + sG[ci + 1]
                      - 4.0f * sG[ci];
            int gy = (Y0 + y - 1) & 511, gx = (X0 + x - 1) & 511;
            sERR[y * STR + x] = c1g[(gy << 9) + gx] - sC0[ci] - lap;
        }
    }
    __syncthreads();

    // --- loss: each thread 4 pixels
    float acc = 0.f;
    int px = tid & 63, py0 = tid >> 6;
    #pragma unroll
    for (int r = 0; r < 4; ++r) {
        int py = py0 + (r << 2);
        int wp = (py + 1) * STR + (px + 1);
        float wu = sWU[wp], wl = sWL[wp];
        float oii_p = wu + wl + sWU[wp + STR] + sWL[wp + 1];
        float oii_u = sWU[wp - STR] + sWL[wp - STR] + wu + sWL[wp - STR + 1];
        float oii_l = sWU[wp - 1] + sWL[wp - 1] + sWU[wp + STR - 1] + wl;
        float e = sERR[wp], eu = sERR[wp - STR], el = sERR[wp - 1];
        float det0 = oii_p * oii_u - wu * wu;
        float l0 = det0 + __fdividef(e * e * oii_u + eu * eu * oii_p + 2.0f * e * eu * wu, det0);
        float det1 = oii_p * oii_l - wl * wl;
        float l1 = det1 + __fdividef(e * e * oii_l + el * el * oii_p + 2.0f * e * el * wl, det1);
        acc += l0 + l1;
    }
    #pragma unroll
    for (int off = 32; off > 0; off >>= 1)
        acc += __shfl_down(acc, off, 64);
    if ((tid & 63) == 0) wsum[tid >> 6] = acc;
    __syncthreads();
    if (tid == 0)
        partial[bid] = wsum[0] + wsum[1] + wsum[2] + wsum[3];
}

// ---------------- kD: deterministic final reduction ----------------
__global__ __launch_bounds__(TPB) void kD(
    const float* __restrict__ partial, float* __restrict__ out)
{
    __shared__ double sm[TPB];
    double acc = 0.0;
    for (int i = threadIdx.x; i < NTILE; i += TPB)
        acc += (double)partial[i];
    sm[threadIdx.x] = acc;
    __syncthreads();
    #pragma unroll
    for (int s = TPB / 2; s > 0; s >>= 1) {
        if (threadIdx.x < s) sm[threadIdx.x] += sm[threadIdx.x + s];
        __syncthreads();
    }
    if (threadIdx.x == 0)
        out[0] = (float)(0.5 * sm[0] / (double)NROWS);
}

extern "C" void kernel_launch(void* const* d_in, const int* in_sizes, int n_in,
                              void* d_out, int out_size, void* d_ws, size_t ws_size,
                              hipStream_t stream) {
    const float* c     = (const float*)d_in[0];
    const float* g0_w1 = (const float*)d_in[1];
    const float* g0_b1 = (const float*)d_in[2];
    const float* g0_w2 = (const float*)d_in[3];
    const float* g0_b2 = (const float*)d_in[4];
    const float* h_w1  = (const float*)d_in[5];
    const float* h_b1  = (const float*)d_in[6];
    const float* h_w2  = (const float*)d_in[7];
    const float* h_b2  = (const float*)d_in[8];
    float* out = (float*)d_out;

    // ws layout: CH | CG | partial
    float* ws = (float*)d_ws;
    float* CH = ws;
    float* CG = CH + NC * NC;
    float* PARTIAL = CG + NCG;

    kT<<<dim3(1), dim3(128), 0, stream>>>(
        g0_w1, g0_b1, g0_w2, g0_b2, h_w1, h_b1, h_w2, h_b2, CH, CG);
    kF<<<dim3(NTILE), dim3(TPB), 0, stream>>>(c, CH, CG, PARTIAL);
    kD<<<1, dim3(TPB), 0, stream>>>(PARTIAL, out);
}

// Round 7
// 27.796 us; speedup vs baseline: 2.1392x; 1.0275x over previous
//
#include <hip/hip_runtime.h>
#include <math.h>

#define NF   32
#define HGT  512
#define WID  512
#define BAT  8
#define HW   (HGT*WID)        // 262144
#define NPIX (BAT*HW)         // 2097152
#define NROWS (2*NPIX)        // 4194304
#define TPB  256

#define TY   16               // tile height
#define TX   64               // tile width
#define TPT  2                // tiles per block (horizontally adjacent)
#define NBLKF 1024            // kF grid

#define NC   5                // hrrp Chebyshev: degree 4, 5x5 coeffs
#define NCG  5                // g0 Chebyshev: degree 4

#define STR  68               // LDS row stride (words)

#define SC0_N (19*67)         // 1273 staged c0 values
#define SC1_N (17*65)         // 1105 staged c1 values
#define SW_N  (18*66)         // 1188 W points
#define SE_N  (17*65)         // 1105 ERR points

__device__ __forceinline__ float fast_tanh(float x) {
    float e = __expf(2.0f * x);
    return 1.0f - __fdividef(2.0f, e + 1.0f);
}

__device__ __forceinline__ float sload(const float* p) {
    return __int_as_float(__builtin_amdgcn_readfirstlane(__float_as_int(*p)));
}

__device__ __forceinline__ float chebG(float v, const float* CG) {
    float tt = 2.0f * v - 1.0f;
    float t0 = 1.0f, t1 = tt;
    float g = CG[0] + CG[1] * tt;
    #pragma unroll
    for (int p = 2; p < NCG; ++p) {
        float t2 = 2.0f * tt * t1 - t0;
        g += CG[p] * t2;
        t0 = t1; t1 = t2;
    }
    return g;
}

// ---------------- kT: build Chebyshev coefficients ----------------
__global__ __launch_bounds__(128) void kT(
    const float* __restrict__ g0_w1, const float* __restrict__ g0_b1,
    const float* __restrict__ g0_w2, const float* __restrict__ g0_b2,
    const float* __restrict__ h_w1,  const float* __restrict__ h_b1,
    const float* __restrict__ h_w2,  const float* __restrict__ h_b2,
    float* __restrict__ CH, float* __restrict__ CG)
{
    __shared__ float cp[NC * NC];
    __shared__ float cg[NCG * NCG];
    __shared__ float F[NC * NC];
    __shared__ float Fg[NCG];
    int t = threadIdx.x;
    if (t < NC * NC) {
        int p = t / NC, i = t - NC * p;
        cp[t] = cosf((float)M_PI * (float)p * ((float)i + 0.5f) / (float)NC);
    } else if (t < NC * NC + NCG * NCG) {
        int u = t - NC * NC;
        int p = u / NCG, i = u - NCG * p;
        cg[u] = cosf((float)M_PI * (float)p * ((float)i + 0.5f) / (float)NCG);
    }
    __syncthreads();
    if (t < NC * NC) {
        int i = t / NC, j = t - NC * i;
        float x = 0.5f * (cp[NC + i] + 1.0f);
        float y = 0.5f * (cp[NC + j] + 1.0f);
        float s = 0.f;
        #pragma unroll
        for (int k = 0; k < NF; ++k) {
            float w0 = h_w1[k], w1 = h_w1[NF + k], bb = h_b1[k], w2 = h_w2[k];
            s += (fast_tanh(x * w0 + y * w1 + bb) + fast_tanh(y * w0 + x * w1 + bb)) * w2;
        }
        F[t] = 0.5f * s + h_b2[0];
    } else if (t < NC * NC + NCG) {
        int i = t - NC * NC;
        float x = 0.5f * (cg[NCG + i] + 1.0f);
        float g = g0_b2[0];
        #pragma unroll
        for (int k = 0; k < NF; ++k)
            g += fast_tanh(x * g0_w1[k] + g0_b1[k]) * g0_w2[k];
        Fg[i] = g;
    }
    __syncthreads();
    if (t < NC * NC) {
        int p = t / NC, q = t - NC * p;
        float sum = 0.f;
        #pragma unroll
        for (int i = 0; i < NC; ++i)
            #pragma unroll
            for (int j = 0; j < NC; ++j)
                sum += F[i * NC + j] * cp[p * NC + i] * cp[q * NC + j];
        float kp = p ? 1.0f : 0.5f, kq = q ? 1.0f : 0.5f;
        CH[t] = (4.0f / (float)(NC * NC)) * kp * kq * sum;
    } else if (t < NC * NC + NCG) {
        int p = t - NC * NC;
        float sum = 0.f;
        #pragma unroll
        for (int i = 0; i < NCG; ++i)
            sum += Fg[i] * cg[p * NCG + i];
        CG[p] = (2.0f / (float)NCG) * (p ? 1.0f : 0.5f) * sum;
    }
}

// ---------------- kF: 2-tiles-per-block, async-staged, 2 barriers/tile ----
__global__ __launch_bounds__(TPB, 4) void kF(
    const float* __restrict__ c, const float* __restrict__ CHg,
    const float* __restrict__ CGg, float* __restrict__ partial)
{
    __shared__ float sC0[20 * STR];   // padded for unmasked stage writes
    __shared__ float sG [20 * STR];
    __shared__ float sC1[20 * STR];
    __shared__ float sWU[18 * STR];
    __shared__ float sWL[18 * STR];
    __shared__ float sERR[17 * STR];
    __shared__ float wsum[4];

    float CH[NC * NC], CG[NCG];
    #pragma unroll
    for (int i = 0; i < NC * NC; ++i) CH[i] = sload(CHg + i);
    #pragma unroll
    for (int i = 0; i < NCG; ++i)     CG[i] = sload(CGg + i);

    int tid = threadIdx.x;
    int bid = blockIdx.x;
    // XCD chunked swizzle (1024 % 8 == 0 -> bijective): XCD x gets one image
    int swz = ((bid & 7) << 7) + (bid >> 3);
    int img = swz >> 7;
    int rem = swz & 127;
    int ty  = rem >> 2;               // 0..31
    int txp = rem & 3;                // 0..3 (pair of 64-wide tiles)
    int Y0  = ty << 4;
    const float* c0g = c + (size_t)img * 2 * HW;
    const float* c1g = c0g + HW;

    // ---- prologue: stage tile 0 (c0 19x67, c1 17x65, G) ----
    {
        int X0 = (txp << 1) << 6;
        float s0[5], s1[5];
        #pragma unroll
        for (int r = 0; r < 5; ++r) {
            int i = tid + r * TPB;
            int y = i / 67, x = i - 67 * y;
            s0[r] = c0g[(((Y0 + y - 2) & 511) << 9) + ((X0 + x - 2) & 511)];
        }
        #pragma unroll
        for (int r = 0; r < 5; ++r) {
            int i = tid + r * TPB;
            int y = i / 65, x = i - 65 * y;
            s1[r] = c1g[(((Y0 + y - 1) & 511) << 9) + ((X0 + x - 1) & 511)];
        }
        #pragma unroll
        for (int r = 0; r < 5; ++r) {
            int i = tid + r * TPB;
            int y = i / 67, x = i - 67 * y;
            sC0[y * STR + x] = s0[r];
            sG [y * STR + x] = chebG(s0[r], CG);
        }
        #pragma unroll
        for (int r = 0; r < 5; ++r) {
            int i = tid + r * TPB;
            int y = i / 65, x = i - 65 * y;
            sC1[y * STR + x] = s1[r];
        }
    }
    __syncthreads();

    float acc = 0.f;
    #pragma unroll
    for (int q = 0; q < TPT; ++q) {
        // ---- issue prefetch for next tile (in flight across phase 1) ----
        int nq = (q + 1 < TPT) ? q + 1 : q;   // last iter reloads self (L1-hit)
        int Xn = ((txp << 1) + nq) << 6;
        float n0[5], n1[5];
        #pragma unroll
        for (int r = 0; r < 5; ++r) {
            int i = tid + r * TPB;
            int y = i / 67, x = i - 67 * y;
            n0[r] = c0g[(((Y0 + y - 2) & 511) << 9) + ((Xn + x - 2) & 511)];
        }
        #pragma unroll
        for (int r = 0; r < 5; ++r) {
            int i = tid + r * TPB;
            int y = i / 65, x = i - 65 * y;
            n1[r] = c1g[(((Y0 + y - 1) & 511) << 9) + ((Xn + x - 1) & 511)];
        }

        // ---- phase 1: W (18x66) and ERR (17x65), both read-only on staged ----
        #pragma unroll
        for (int r = 0; r < 5; ++r) {
            int i = tid + r * TPB;
            if (i < SW_N) {
                int y = i / 66, x = i - y * 66;
                int ci = (y + 1) * STR + (x + 1);
                float a  = sC0[ci];
                float uu = sC0[ci - STR];
                float ll = sC0[ci - 1];

                float ta = 2.0f * a - 1.0f;
                float T[NC];
                T[0] = 1.0f; T[1] = ta;
                #pragma unroll
                for (int p = 2; p < NC; ++p) T[p] = 2.0f * ta * T[p - 1] - T[p - 2];
                float s[NC];
                #pragma unroll
                for (int qq = 0; qq < NC; ++qq) {
                    float a2 = CH[qq];
                    #pragma unroll
                    for (int p = 1; p < NC; ++p) a2 += CH[p * NC + qq] * T[p];
                    s[qq] = a2;
                }
                float tu = 2.0f * uu - 1.0f;
                float u0 = 1.0f, u1 = tu;
                float wu = s[0] + s[1] * tu;
                #pragma unroll
                for (int qq = 2; qq < NC; ++qq) {
                    float u2 = 2.0f * tu * u1 - u0;
                    wu += s[qq] * u2;
                    u0 = u1; u1 = u2;
                }
                float tl = 2.0f * ll - 1.0f;
                float l0 = 1.0f, l1 = tl;
                float wl = s[0] + s[1] * tl;
                #pragma unroll
                for (int qq = 2; qq < NC; ++qq) {
                    float l2 = 2.0f * tl * l1 - l0;
                    wl += s[qq] * l2;
                    l0 = l1; l1 = l2;
                }
                sWU[y * STR + x] = wu;
                sWL[y * STR + x] = wl;
            }
        }
        #pragma unroll
        for (int r = 0; r < 5; ++r) {
            int i = tid + r * TPB;
            if (i < SE_N) {
                int y = i / 65, x = i - y * 65;
                int ci = (y + 1) * STR + (x + 1);
                float lap = sG[ci - STR] + sG[ci + STR] + sG[ci - 1] + sG[ci + 1]
                          - 4.0f * sG[ci];
                sERR[y * STR + x] = sC1[y * STR + x] - sC0[ci] - lap;
            }
        }
        __syncthreads();

        // ---- phase 2: loss (reads sW/sERR) + write prefetched tile ----
        int px = tid & 63, py0 = tid >> 6;
        #pragma unroll
        for (int r = 0; r < 4; ++r) {
            int py = py0 + (r << 2);
            int wp = (py + 1) * STR + (px + 1);
            float wu = sWU[wp], wl = sWL[wp];
            float oii_p = wu + wl + sWU[wp + STR] + sWL[wp + 1];
            float oii_u = sWU[wp - STR] + sWL[wp - STR] + wu + sWL[wp - STR + 1];
            float oii_l = sWU[wp - 1] + sWL[wp - 1] + sWU[wp + STR - 1] + wl;
            float e = sERR[wp], eu = sERR[wp - STR], el = sERR[wp - 1];
            float det0 = oii_p * oii_u - wu * wu;
            float l0 = det0 + __fdividef(e * e * oii_u + eu * eu * oii_p + 2.0f * e * eu * wu, det0);
            float det1 = oii_p * oii_l - wl * wl;
            float l1 = det1 + __fdividef(e * e * oii_l + el * el * oii_p + 2.0f * e * el * wl, det1);
            acc += l0 + l1;
        }
        #pragma unroll
        for (int r = 0; r < 5; ++r) {
            int i = tid + r * TPB;
            int y = i / 67, x = i - 67 * y;
            sC0[y * STR + x] = n0[r];
            sG [y * STR + x] = chebG(n0[r], CG);
        }
        #pragma unroll
        for (int r = 0; r < 5; ++r) {
            int i = tid + r * TPB;
            int y = i / 65, x = i - 65 * y;
            sC1[y * STR + x] = n1[r];
        }
        __syncthreads();
    }

    // ---- block reduce ----
    #pragma unroll
    for (int off = 32; off > 0; off >>= 1)
        acc += __shfl_down(acc, off, 64);
    if ((tid & 63) == 0) wsum[tid >> 6] = acc;
    __syncthreads();
    if (tid == 0)
        partial[bid] = wsum[0] + wsum[1] + wsum[2] + wsum[3];
}

// ---------------- kD: deterministic final reduction ----------------
__global__ __launch_bounds__(TPB) void kD(
    const float* __restrict__ partial, float* __restrict__ out)
{
    __shared__ double sm[TPB];
    double acc = 0.0;
    for (int i = threadIdx.x; i < NBLKF; i += TPB)
        acc += (double)partial[i];
    sm[threadIdx.x] = acc;
    __syncthreads();
    #pragma unroll
    for (int s = TPB / 2; s > 0; s >>= 1) {
        if (threadIdx.x < s) sm[threadIdx.x] += sm[threadIdx.x + s];
        __syncthreads();
    }
    if (threadIdx.x == 0)
        out[0] = (float)(0.5 * sm[0] / (double)NROWS);
}

extern "C" void kernel_launch(void* const* d_in, const int* in_sizes, int n_in,
                              void* d_out, int out_size, void* d_ws, size_t ws_size,
                              hipStream_t stream) {
    const float* c     = (const float*)d_in[0];
    const float* g0_w1 = (const float*)d_in[1];
    const float* g0_b1 = (const float*)d_in[2];
    const float* g0_w2 = (const float*)d_in[3];
    const float* g0_b2 = (const float*)d_in[4];
    const float* h_w1  = (const float*)d_in[5];
    const float* h_b1  = (const float*)d_in[6];
    const float* h_w2  = (const float*)d_in[7];
    const float* h_b2  = (const float*)d_in[8];
    float* out = (float*)d_out;

    // ws layout: CH | CG | partial
    float* ws = (float*)d_ws;
    float* CH = ws;
    float* CG = CH + NC * NC;
    float* PARTIAL = CG + NCG;

    kT<<<dim3(1), dim3(128), 0, stream>>>(
        g0_w1, g0_b1, g0_w2, g0_b2, h_w1, h_b1, h_w2, h_b2, CH, CG);
    kF<<<dim3(NBLKF), dim3(TPB), 0, stream>>>(c, CH, CG, PARTIAL);
    kD<<<1, dim3(TPB), 0, stream>>>(PARTIAL, out);
}

// Round 8
// 22.030 us; speedup vs baseline: 2.6992x; 1.2618x over previous
//
#include <hip/hip_runtime.h>
#include <math.h>

#define NF   32
#define HGT  512
#define WID  512
#define BAT  8
#define HW   (HGT*WID)        // 262144
#define NPIX (BAT*HW)         // 2097152
#define NROWS (2*NPIX)        // 4194304
#define TPB  256

#define RROWS 4               // rows per wave strip
#define NBLKF 256             // 256 blocks x 4 waves = 1024 strips

#define NC   5                // hrrp Chebyshev: degree 4, 5x5 coeffs
#define NCG  5                // g0 Chebyshev: degree 4

__device__ __forceinline__ float fast_tanh(float x) {
    float e = __expf(2.0f * x);
    return 1.0f - __fdividef(2.0f, e + 1.0f);
}

__device__ __forceinline__ float sload(const float* p) {
    return __int_as_float(__builtin_amdgcn_readfirstlane(__float_as_int(*p)));
}

__device__ __forceinline__ float chebG(float v, const float (&CG)[NCG]) {
    float tt = 2.0f * v - 1.0f;
    float T2 = 2.0f * tt * tt - 1.0f;
    float T3 = 2.0f * tt * T2 - tt;
    float T4 = 2.0f * tt * T3 - T2;
    return CG[0] + CG[1] * tt + CG[2] * T2 + CG[3] * T3 + CG[4] * T4;
}

// ---------------- kT: build Chebyshev coefficients (unchanged, validated) ----
__global__ __launch_bounds__(128) void kT(
    const float* __restrict__ g0_w1, const float* __restrict__ g0_b1,
    const float* __restrict__ g0_w2, const float* __restrict__ g0_b2,
    const float* __restrict__ h_w1,  const float* __restrict__ h_b1,
    const float* __restrict__ h_w2,  const float* __restrict__ h_b2,
    float* __restrict__ CH, float* __restrict__ CG)
{
    __shared__ float cp[NC * NC];
    __shared__ float cg[NCG * NCG];
    __shared__ float F[NC * NC];
    __shared__ float Fg[NCG];
    int t = threadIdx.x;
    if (t < NC * NC) {
        int p = t / NC, i = t - NC * p;
        cp[t] = cosf((float)M_PI * (float)p * ((float)i + 0.5f) / (float)NC);
    } else if (t < NC * NC + NCG * NCG) {
        int u = t - NC * NC;
        int p = u / NCG, i = u - NCG * p;
        cg[u] = cosf((float)M_PI * (float)p * ((float)i + 0.5f) / (float)NCG);
    }
    __syncthreads();
    if (t < NC * NC) {
        int i = t / NC, j = t - NC * i;
        float x = 0.5f * (cp[NC + i] + 1.0f);
        float y = 0.5f * (cp[NC + j] + 1.0f);
        float s = 0.f;
        #pragma unroll
        for (int k = 0; k < NF; ++k) {
            float w0 = h_w1[k], w1 = h_w1[NF + k], bb = h_b1[k], w2 = h_w2[k];
            s += (fast_tanh(x * w0 + y * w1 + bb) + fast_tanh(y * w0 + x * w1 + bb)) * w2;
        }
        F[t] = 0.5f * s + h_b2[0];
    } else if (t < NC * NC + NCG) {
        int i = t - NC * NC;
        float x = 0.5f * (cg[NCG + i] + 1.0f);
        float g = g0_b2[0];
        #pragma unroll
        for (int k = 0; k < NF; ++k)
            g += fast_tanh(x * g0_w1[k] + g0_b1[k]) * g0_w2[k];
        Fg[i] = g;
    }
    __syncthreads();
    if (t < NC * NC) {
        int p = t / NC, q = t - NC * p;
        float sum = 0.f;
        #pragma unroll
        for (int i = 0; i < NC; ++i)
            #pragma unroll
            for (int j = 0; j < NC; ++j)
                sum += F[i * NC + j] * cp[p * NC + i] * cp[q * NC + j];
        float kp = p ? 1.0f : 0.5f, kq = q ? 1.0f : 0.5f;
        CH[t] = (4.0f / (float)(NC * NC)) * kp * kq * sum;
    } else if (t < NC * NC + NCG) {
        int p = t - NC * NC;
        float sum = 0.f;
        #pragma unroll
        for (int i = 0; i < NCG; ++i)
            sum += Fg[i] * cg[p * NCG + i];
        CG[p] = (2.0f / (float)NCG) * (p ? 1.0f : 0.5f) * sum;
    }
}

// ---------------- register-streaming helpers ----------------
__device__ __forceinline__ void loadrow(const float* __restrict__ base, int y,
                                        int xb, float (&d)[8]) {
    const float* r = base + ((y & 511) << 9) + xb;
    float4 a = *(const float4*)r;
    float4 b = *(const float4*)(r + 4);
    d[0]=a.x; d[1]=a.y; d[2]=a.z; d[3]=a.w;
    d[4]=b.x; d[5]=b.y; d[6]=b.z; d[7]=b.w;
}

__device__ __forceinline__ void grow(const float (&v)[8], const float (&CG)[NCG],
                                     float (&g)[8]) {
    #pragma unroll
    for (int x = 0; x < 8; ++x) g[x] = chebG(v[x], CG);
}

// WU[x]=hrrp(a[x], up[x]); WL[x]=hrrp(a[x], a[x-1]) with x-wrap via lane shuffle
__device__ __forceinline__ void wrow(const float (&a)[8], const float (&up)[8],
                                     int lane, const float (&CH)[NC*NC],
                                     float (&WU)[8], float (&WL)[8]) {
    float lft = __shfl(a[7], (lane + 63) & 63, 64);
    #pragma unroll
    for (int x = 0; x < 8; ++x) {
        float ta = 2.f * a[x] - 1.f;
        float T2 = 2.f*ta*ta - 1.f;
        float T3 = 2.f*ta*T2 - ta;
        float T4 = 2.f*ta*T3 - T2;
        float s0 = CH[0] + CH[5]*ta + CH[10]*T2 + CH[15]*T3 + CH[20]*T4;
        float s1 = CH[1] + CH[6]*ta + CH[11]*T2 + CH[16]*T3 + CH[21]*T4;
        float s2 = CH[2] + CH[7]*ta + CH[12]*T2 + CH[17]*T3 + CH[22]*T4;
        float s3 = CH[3] + CH[8]*ta + CH[13]*T2 + CH[18]*T3 + CH[23]*T4;
        float s4 = CH[4] + CH[9]*ta + CH[14]*T2 + CH[19]*T3 + CH[24]*T4;
        float tu = 2.f*up[x] - 1.f;
        float U2 = 2.f*tu*tu - 1.f, U3 = 2.f*tu*U2 - tu, U4 = 2.f*tu*U3 - U2;
        WU[x] = s0 + s1*tu + s2*U2 + s3*U3 + s4*U4;
        float lv = x ? a[x-1] : lft;
        float tl = 2.f*lv - 1.f;
        float L2_ = 2.f*tl*tl - 1.f, L3_ = 2.f*tl*L2_ - tl, L4_ = 2.f*tl*L3_ - L2_;
        WL[x] = s0 + s1*tl + s2*L2_ + s3*L3_ + s4*L4_;
    }
}

// ERR[r] = c1[r] - c0[r] - (Gup + Gdn + Gl + Gr - 4*Gc)
__device__ __forceinline__ void errrow(const float (&c1r)[8], const float (&c0c)[8],
                                       const float (&Gup)[8], const float (&Gc)[8],
                                       const float (&Gdn)[8], int lane,
                                       float (&E)[8]) {
    float lf = __shfl(Gc[7], (lane + 63) & 63, 64);
    float rt = __shfl(Gc[0], (lane + 1) & 63, 64);
    #pragma unroll
    for (int x = 0; x < 8; ++x) {
        float gl = x ? Gc[x-1] : lf;
        float gr = (x < 7) ? Gc[x+1] : rt;
        float lap = Gup[x] + Gdn[x] + gl + gr - 4.f * Gc[x];
        E[x] = c1r[x] - c0c[x] - lap;
    }
}

// loss at row y-1: Wp=W[y-1], Wp2=W[y-2], WUc=WU[y], Ec=ERR[y-1], Ep=ERR[y-2]
__device__ __forceinline__ float lossrow(
    const float (&WUp)[8],  const float (&WLp)[8],
    const float (&WUp2)[8], const float (&WLp2)[8],
    const float (&WUc)[8],
    const float (&Ec)[8],   const float (&Ep)[8], int lane)
{
    int lm = (lane + 63) & 63, lp = (lane + 1) & 63;
    float wlp_r  = __shfl(WLp[0],  lp, 64);
    float wlp2_r = __shfl(WLp2[0], lp, 64);
    float wup_l  = __shfl(WUp[7],  lm, 64);
    float wlp_l  = __shfl(WLp[7],  lm, 64);
    float wuc_l  = __shfl(WUc[7],  lm, 64);
    float ec_l   = __shfl(Ec[7],   lm, 64);
    float acc = 0.f;
    #pragma unroll
    for (int x = 0; x < 8; ++x) {
        float wu = WUp[x], wl = WLp[x];
        float wlR  = (x < 7) ? WLp[x+1]  : wlp_r;
        float wl2R = (x < 7) ? WLp2[x+1] : wlp2_r;
        float wuL  = x ? WUp[x-1] : wup_l;
        float wlL  = x ? WLp[x-1] : wlp_l;
        float wucL = x ? WUc[x-1] : wuc_l;
        float eL   = x ? Ec[x-1]  : ec_l;
        float oii_p = wu + wl + WUc[x] + wlR;
        float oii_u = WUp2[x] + WLp2[x] + wu + wl2R;
        float oii_l = wuL + wlL + wucL + wl;
        float e = Ec[x], eu = Ep[x];
        float det0 = oii_p * oii_u - wu * wu;
        float l0 = det0 + __fdividef(e*e*oii_u + eu*eu*oii_p + 2.f*e*eu*wu, det0);
        float det1 = oii_p * oii_l - wl * wl;
        float l1 = det1 + __fdividef(e*e*oii_l + eL*eL*oii_p + 2.f*e*eL*wl, det1);
        acc += l0 + l1;
    }
    return acc;
}

// ---------------- kF: wave-autonomous register-streaming ----------------
__global__ __launch_bounds__(TPB, 1) void kF(
    const float* __restrict__ c, const float* __restrict__ CHg,
    const float* __restrict__ CGg, float* __restrict__ partial)
{
    __shared__ float wsum[4];

    float CH[NC * NC], CG[NCG];
    #pragma unroll
    for (int i = 0; i < NC * NC; ++i) CH[i] = sload(CHg + i);
    #pragma unroll
    for (int i = 0; i < NCG; ++i)     CG[i] = sload(CGg + i);

    int tid  = threadIdx.x;
    int lane = tid & 63;
    // XCD chunked swizzle: XCD x owns blocks [32x, 32x+32) -> exactly one image
    int sb   = ((blockIdx.x & 7) << 5) + (blockIdx.x >> 3);
    int wid  = (sb << 2) + (tid >> 6);      // 0..1023 strips
    int img  = wid >> 7;
    int Y0   = (wid & 127) << 2;            // RROWS=4
    const float* c0g = c + (size_t)img * 2 * HW;
    const float* c1g = c0g + HW;
    int xb = lane << 3;                     // 8 contiguous cols per lane

    // circular register buffers
    float c0s[2][8], Gs[3][8], WUs[3][8], WLs[3][8], Es[2][8];

    // ---- warmup: state for first step y = Y0+1 ----
    {
        float c0m2[8], c0m1[8], Gm2[8], c1t[8];
        loadrow(c0g, Y0 - 2, xb, c0m2);
        loadrow(c0g, Y0 - 1, xb, c0m1);
        loadrow(c0g, Y0,     xb, c0s[0]);
        loadrow(c1g, Y0 - 1, xb, c1t);
        grow(c0m2, CG, Gm2);
        grow(c0m1, CG, Gs[0]);              // G[Y0-1]
        grow(c0s[0], CG, Gs[1]);            // G[Y0]
        wrow(c0m1, c0m2, lane, CH, WUs[0], WLs[0]);   // W[Y0-1]
        wrow(c0s[0], c0m1, lane, CH, WUs[1], WLs[1]); // W[Y0]
        errrow(c1t, c0m1, Gm2, Gs[0], Gs[1], lane, Es[0]); // ERR[Y0-1]
    }

    float acc = 0.f;
    #pragma unroll
    for (int k = 0; k < RROWS; ++k) {
        int y = Y0 + 1 + k;
        const int icC = (k + 1) & 1, icP = k & 1;
        const int ig2 = k % 3, ig1 = (k + 1) % 3, igC = (k + 2) % 3;
        const int iw2 = k % 3, iw1 = (k + 1) % 3, iwC = (k + 2) % 3;
        const int ieP = k & 1, ieC = (k + 1) & 1;
        float c1r[8];
        loadrow(c0g, y,     xb, c0s[icC]);
        loadrow(c1g, y - 1, xb, c1r);
        grow(c0s[icC], CG, Gs[igC]);
        wrow(c0s[icC], c0s[icP], lane, CH, WUs[iwC], WLs[iwC]);
        errrow(c1r, c0s[icP], Gs[ig2], Gs[ig1], Gs[igC], lane, Es[ieC]);
        acc += lossrow(WUs[iw1], WLs[iw1], WUs[iw2], WLs[iw2], WUs[iwC],
                       Es[ieC], Es[ieP], lane);
    }

    // ---- block reduce (deterministic) ----
    #pragma unroll
    for (int off = 32; off > 0; off >>= 1)
        acc += __shfl_down(acc, off, 64);
    if (lane == 0) wsum[tid >> 6] = acc;
    __syncthreads();
    if (tid == 0)
        partial[blockIdx.x] = wsum[0] + wsum[1] + wsum[2] + wsum[3];
}

// ---------------- kD: deterministic final reduction ----------------
__global__ __launch_bounds__(TPB) void kD(
    const float* __restrict__ partial, float* __restrict__ out)
{
    __shared__ double sm[TPB];
    double acc = 0.0;
    for (int i = threadIdx.x; i < NBLKF; i += TPB)
        acc += (double)partial[i];
    sm[threadIdx.x] = acc;
    __syncthreads();
    #pragma unroll
    for (int s = TPB / 2; s > 0; s >>= 1) {
        if (threadIdx.x < s) sm[threadIdx.x] += sm[threadIdx.x + s];
        __syncthreads();
    }
    if (threadIdx.x == 0)
        out[0] = (float)(0.5 * sm[0] / (double)NROWS);
}

extern "C" void kernel_launch(void* const* d_in, const int* in_sizes, int n_in,
                              void* d_out, int out_size, void* d_ws, size_t ws_size,
                              hipStream_t stream) {
    const float* c     = (const float*)d_in[0];
    const float* g0_w1 = (const float*)d_in[1];
    const float* g0_b1 = (const float*)d_in[2];
    const float* g0_w2 = (const float*)d_in[3];
    const float* g0_b2 = (const float*)d_in[4];
    const float* h_w1  = (const float*)d_in[5];
    const float* h_b1  = (const float*)d_in[6];
    const float* h_w2  = (const float*)d_in[7];
    const float* h_b2  = (const float*)d_in[8];
    float* out = (float*)d_out;

    // ws layout: CH | CG | partial
    float* ws = (float*)d_ws;
    float* CH = ws;
    float* CG = CH + NC * NC;
    float* PARTIAL = CG + NCG;

    kT<<<dim3(1), dim3(128), 0, stream>>>(
        g0_w1, g0_b1, g0_w2, g0_b2, h_w1, h_b1, h_w2, h_b2, CH, CG);
    kF<<<dim3(NBLKF), dim3(TPB), 0, stream>>>(c, CH, CG, PARTIAL);
    kD<<<1, dim3(TPB), 0, stream>>>(PARTIAL, out);
}